// Round 1
// baseline (467.890 us; speedup 1.0000x reference)
//
#include <hip/hip_runtime.h>

// ---------------------------------------------------------------------------
// Channel attention (XCA-style): B=4, N=4096, C=768, H=8, HD=96, fp32 in/out.
// Strategy: bf16 MFMA for all GEMM-shaped work, fp32 accumulation throughout.
// ---------------------------------------------------------------------------

using bf16x8 = __attribute__((ext_vector_type(8))) short;
using f32x4  = __attribute__((ext_vector_type(4))) float;

#define SCALE_ 0.10206207261596575f   // 96^-0.5

__device__ __forceinline__ unsigned short f2bf(float f) {
    unsigned int u = __builtin_bit_cast(unsigned int, f);
    u += 0x7FFFu + ((u >> 16) & 1u);          // RNE, finite inputs only
    return (unsigned short)(u >> 16);
}
__device__ __forceinline__ float bf2f(unsigned short h) {
    unsigned int u = ((unsigned int)h) << 16;
    return __builtin_bit_cast(float, u);
}

// ---------------------------------------------------------------------------
// Weight transpose + fp32->bf16: W[K][N] -> Wt[N][K] (so MFMA B-frags read
// k-contiguous from LDS). block(32,8), grid(N/32, K/32).
// ---------------------------------------------------------------------------
__global__ void transpose_to_bf16(const float* __restrict__ W,
                                  unsigned short* __restrict__ Wt,
                                  int K, int N)
{
    __shared__ float tile[32][33];
    int n0 = blockIdx.x * 32, k0 = blockIdx.y * 32;
    int tx = threadIdx.x, ty = threadIdx.y;
    #pragma unroll
    for (int i = 0; i < 32; i += 8)
        tile[ty + i][tx] = W[(size_t)(k0 + ty + i) * N + n0 + tx];
    __syncthreads();
    #pragma unroll
    for (int i = 0; i < 32; i += 8)
        Wt[(size_t)(n0 + ty + i) * K + k0 + tx] = f2bf(tile[tx][ty + i]);
}

// ---------------------------------------------------------------------------
// GEMM: C[M][N] = A[M][K] * W[K][N], W given transposed as Bt[N][K] bf16.
// A is fp32 (converted during staging) or bf16. 128x128 tile, BK=32,
// 4 waves each computing 64x64 via 4x4 of 16x16x32 MFMA.
// LDS stride 40 ushorts = 80B: 16B-aligned rows, bank-balanced b128 reads.
// ---------------------------------------------------------------------------
template<bool A_FP32, bool OUT_F32_BIAS>
__global__ __launch_bounds__(256) void gemm_bt(
    const void* __restrict__ Av, const unsigned short* __restrict__ Bt,
    const float* __restrict__ bias, void* __restrict__ Cv,
    int M, int N, int K)
{
    __shared__ unsigned short As[128][40];
    __shared__ unsigned short Bs[128][40];
    const int bm = blockIdx.y * 128, bn = blockIdx.x * 128;
    const int t = threadIdx.x, lane = t & 63, w = t >> 6;
    const int wm = (w >> 1) * 64, wn = (w & 1) * 64;
    const int mf = lane & 15, k8 = (lane >> 4) * 8;
    f32x4 acc[4][4] = {};

    for (int k0 = 0; k0 < K; k0 += 32) {
        if constexpr (A_FP32) {
            const float* A = (const float*)Av;
            int row = t >> 3, kv = (t & 7) * 4;
            #pragma unroll
            for (int p = 0; p < 4; p++) {
                float4 v = *(const float4*)&A[(size_t)(bm + row + p * 32) * K + k0 + kv];
                ushort4 hh;
                hh.x = f2bf(v.x); hh.y = f2bf(v.y); hh.z = f2bf(v.z); hh.w = f2bf(v.w);
                *(ushort4*)&As[row + p * 32][kv] = hh;
            }
        } else {
            const unsigned short* A = (const unsigned short*)Av;
            int row = t >> 2, kv = (t & 3) * 8;
            #pragma unroll
            for (int p = 0; p < 2; p++)
                *(uint4*)&As[row + p * 64][kv] =
                    *(const uint4*)&A[(size_t)(bm + row + p * 64) * K + k0 + kv];
        }
        {
            int row = t >> 2, kv = (t & 3) * 8;
            #pragma unroll
            for (int p = 0; p < 2; p++)
                *(uint4*)&Bs[row + p * 64][kv] =
                    *(const uint4*)&Bt[(size_t)(bn + row + p * 64) * K + k0 + kv];
        }
        __syncthreads();
        bf16x8 a[4], b[4];
        #pragma unroll
        for (int i = 0; i < 4; i++) a[i] = *(const bf16x8*)&As[wm + i * 16 + mf][k8];
        #pragma unroll
        for (int j = 0; j < 4; j++) b[j] = *(const bf16x8*)&Bs[wn + j * 16 + mf][k8];
        #pragma unroll
        for (int i = 0; i < 4; i++)
            #pragma unroll
            for (int j = 0; j < 4; j++)
                acc[i][j] = __builtin_amdgcn_mfma_f32_16x16x32_bf16(a[i], b[j], acc[i][j], 0, 0, 0);
        __syncthreads();
    }

    // C/D layout (m89-verified): col = lane&15, row = (lane>>4)*4 + r
    #pragma unroll
    for (int i = 0; i < 4; i++) {
        #pragma unroll
        for (int j = 0; j < 4; j++) {
            int col  = bn + wn + j * 16 + mf;
            int row0 = bm + wm + i * 16 + (lane >> 4) * 4;
            if constexpr (OUT_F32_BIAS) {
                float bv = bias[col];
                float* C = (float*)Cv;
                #pragma unroll
                for (int r = 0; r < 4; r++)
                    C[(size_t)(row0 + r) * N + col] = acc[i][j][r] + bv;
            } else {
                unsigned short* C = (unsigned short*)Cv;
                #pragma unroll
                for (int r = 0; r < 4; r++)
                    C[(size_t)(row0 + r) * N + col] = f2bf(acc[i][j][r]);
            }
        }
    }
}

// ---------------------------------------------------------------------------
// Column sum-of-squares over the token axis (for L2-normalize over N).
// X is bf16 [b][4096][row_stride], uses columns 0..767. grid(3,4,8), 256 thr.
// ---------------------------------------------------------------------------
__global__ void col_ssq(const unsigned short* __restrict__ X,
                        float* __restrict__ out, int row_stride)
{
    int t = threadIdx.x;
    int c = blockIdx.x * 256 + t;
    int b = blockIdx.y, chunk = blockIdx.z;
    size_t base = ((size_t)b * 4096 + (size_t)chunk * 512) * row_stride + c;
    float s = 0.f;
    for (int n = 0; n < 512; n++) {
        float v = bf2f(X[base + (size_t)n * row_stride]);
        s += v * v;
    }
    atomicAdd(&out[b * 768 + c], s);
}

// ---------------------------------------------------------------------------
// Partial gram: S_part[b][h][chunk][96][96] = sum over 512 tokens of
// Q[:,d] * K[:,e]. fp32 VALU, 6x6 register tile per thread. grid(8,8,4).
// ---------------------------------------------------------------------------
__global__ __launch_bounds__(256) void s_partial(
    const unsigned short* __restrict__ Q, const unsigned short* __restrict__ KV,
    float* __restrict__ Spart)
{
    __shared__ float Qs[16][100];
    __shared__ float Ks[16][100];
    int chunk = blockIdx.x, h = blockIdx.y, b = blockIdx.z;
    int t = threadIdx.x;
    int d0 = (t >> 4) * 6, e0 = (t & 15) * 6;
    float acc[6][6] = {};
    size_t qbase = ((size_t)b * 4096 + (size_t)chunk * 512) * 768 + h * 96;
    size_t kbase = ((size_t)b * 4096 + (size_t)chunk * 512) * 1536 + h * 96;

    for (int n0 = 0; n0 < 512; n0 += 16) {
        #pragma unroll
        for (int i = 0; i < 6; i++) {
            int idx = t + 256 * i;              // 1536 = 16 rows x 96 cols
            int row = idx / 96, c = idx - row * 96;
            Qs[row][c] = bf2f(Q[qbase + (size_t)(n0 + row) * 768 + c]);
            Ks[row][c] = bf2f(KV[kbase + (size_t)(n0 + row) * 1536 + c]);
        }
        __syncthreads();
        #pragma unroll
        for (int n = 0; n < 16; n++) {
            float2 qa = *(const float2*)&Qs[n][d0];
            float2 qb = *(const float2*)&Qs[n][d0 + 2];
            float2 qc = *(const float2*)&Qs[n][d0 + 4];
            float2 ka = *(const float2*)&Ks[n][e0];
            float2 kb = *(const float2*)&Ks[n][e0 + 2];
            float2 kc = *(const float2*)&Ks[n][e0 + 4];
            float qv[6] = {qa.x, qa.y, qb.x, qb.y, qc.x, qc.y};
            float kv[6] = {ka.x, ka.y, kb.x, kb.y, kc.x, kc.y};
            #pragma unroll
            for (int i = 0; i < 6; i++)
                #pragma unroll
                for (int j = 0; j < 6; j++)
                    acc[i][j] += qv[i] * kv[j];
        }
        __syncthreads();
    }
    float* outp = Spart + ((size_t)((b * 8 + h) * 8 + chunk)) * 9216;
    #pragma unroll
    for (int i = 0; i < 6; i++)
        #pragma unroll
        for (int j = 0; j < 6; j++)
            outp[(d0 + i) * 96 + e0 + j] = acc[i][j];
}

// ---------------------------------------------------------------------------
// Reduce partials, apply SCALE and the two 1/max(||.||,eps) norms as outer
// scaling, row-softmax over e (96), emit P bf16 [bh][96][96]. 32 blocks x 128.
// ---------------------------------------------------------------------------
__global__ void softmax_k(const float* __restrict__ Spart,
                          const float* __restrict__ ssq,
                          unsigned short* __restrict__ P)
{
    __shared__ float Sf[96 * 97];
    __shared__ float qsl[96];
    __shared__ float ksl[96];
    int bh = blockIdx.x, t = threadIdx.x;
    int b = bh >> 3, h = bh & 7;
    if (t < 96) {
        float nq = sqrtf(ssq[b * 768 + h * 96 + t]);
        qsl[t] = 1.0f / fmaxf(nq, 1e-12f);
        float nk = sqrtf(ssq[3072 + b * 768 + h * 96 + t]);
        ksl[t] = 1.0f / fmaxf(nk, 1e-12f);
    }
    __syncthreads();
    for (int idx = t; idx < 9216; idx += 128) {
        float s = 0.f;
        #pragma unroll
        for (int ch = 0; ch < 8; ch++)
            s += Spart[((size_t)(bh * 8 + ch)) * 9216 + idx];
        int d = idx / 96, e = idx - d * 96;
        Sf[d * 97 + e] = s * SCALE_ * qsl[d] * ksl[e];
    }
    __syncthreads();
    if (t < 96) {
        int d = t;
        float m = -1e30f;
        for (int e = 0; e < 96; e++) m = fmaxf(m, Sf[d * 97 + e]);
        float ssum = 0.f;
        for (int e = 0; e < 96; e++) {
            float ex = expf(Sf[d * 97 + e] - m);
            Sf[d * 97 + e] = ex;
            ssum += ex;
        }
        float inv = 1.0f / ssum;
        for (int e = 0; e < 96; e++)
            P[(size_t)bh * 9216 + d * 96 + e] = f2bf(Sf[d * 97 + e] * inv);
    }
}

// ---------------------------------------------------------------------------
// x[n][d] = sum_e V[n][e] * P[d][e] per (b,h). P row-major IS the MFMA
// B-operand layout (lane&15 -> d, k-contiguous e). V A-frags load straight
// from global (lane quads coalesce into 64B lines, each V elem read once).
// grid(32 ntiles, 32 bh), 256 thr; waves own 32 token-rows each.
// ---------------------------------------------------------------------------
__global__ __launch_bounds__(256) void pv_gemm(
    const unsigned short* __restrict__ KV, const unsigned short* __restrict__ P,
    unsigned short* __restrict__ X)
{
    __shared__ unsigned short Ps[96][104];
    int ntile = blockIdx.x, bh = blockIdx.y;
    int b = bh >> 3, h = bh & 7;
    int t = threadIdx.x, lane = t & 63, w = t >> 6;

    const unsigned short* Pg = P + (size_t)bh * 9216;
    #pragma unroll
    for (int i = 0; i < 9; i++) {
        int idx4 = t + 256 * i;                 // 2304 ushort4 chunks
        int row = idx4 / 24, c4 = (idx4 - row * 24) * 4;
        *(ushort4*)&Ps[row][c4] = *(const ushort4*)&Pg[row * 96 + c4];
    }
    __syncthreads();

    const unsigned short* Vbase = KV + (size_t)b * 4096 * 1536 + 768 + h * 96;
    int mf = lane & 15, k8 = (lane >> 4) * 8;
    f32x4 acc[2][6] = {};
    #pragma unroll
    for (int k = 0; k < 3; k++) {
        bf16x8 a[2], bb[6];
        #pragma unroll
        for (int i = 0; i < 2; i++) {
            int row = ntile * 128 + w * 32 + i * 16 + mf;
            a[i] = *(const bf16x8*)&Vbase[(size_t)row * 1536 + k * 32 + k8];
        }
        #pragma unroll
        for (int j = 0; j < 6; j++)
            bb[j] = *(const bf16x8*)&Ps[j * 16 + mf][k * 32 + k8];
        #pragma unroll
        for (int i = 0; i < 2; i++)
            #pragma unroll
            for (int j = 0; j < 6; j++)
                acc[i][j] = __builtin_amdgcn_mfma_f32_16x16x32_bf16(a[i], bb[j], acc[i][j], 0, 0, 0);
    }
    #pragma unroll
    for (int i = 0; i < 2; i++)
        #pragma unroll
        for (int j = 0; j < 6; j++)
            #pragma unroll
            for (int r = 0; r < 4; r++) {
                int n_tok = ntile * 128 + w * 32 + i * 16 + (lane >> 4) * 4 + r;
                int c = h * 96 + j * 16 + mf;
                X[((size_t)b * 4096 + n_tok) * 768 + c] = f2bf(acc[i][j][r]);
            }
}

// ---------------------------------------------------------------------------
extern "C" void kernel_launch(void* const* d_in, const int* in_sizes, int n_in,
                              void* d_out, int out_size, void* d_ws, size_t ws_size,
                              hipStream_t stream)
{
    (void)in_sizes; (void)n_in; (void)out_size; (void)ws_size;
    const float* ctx   = (const float*)d_in[0];
    const float* dep   = (const float*)d_in[1];
    const float* Wq    = (const float*)d_in[2];
    const float* Wkv   = (const float*)d_in[3];
    const float* Wproj = (const float*)d_in[4];
    const float* bproj = (const float*)d_in[5];
    float* out = (float*)d_out;

    char* p = (char*)d_ws;
    auto carve = [&](size_t bytes) {
        char* r = p;
        p += (bytes + 255) & ~(size_t)255;
        return r;
    };
    unsigned short* WqT    = (unsigned short*)carve((size_t)768 * 768 * 2);
    unsigned short* WkvT   = (unsigned short*)carve((size_t)1536 * 768 * 2);
    unsigned short* WprojT = (unsigned short*)carve((size_t)768 * 768 * 2);
    unsigned short* Qb     = (unsigned short*)carve((size_t)16384 * 768 * 2);
    unsigned short* KVb    = (unsigned short*)carve((size_t)16384 * 1536 * 2);
    unsigned short* Xb     = (unsigned short*)carve((size_t)16384 * 768 * 2);
    float*          ssq    = (float*)carve((size_t)2 * 4 * 768 * 4);
    float*          Spart  = (float*)carve((size_t)32 * 8 * 9216 * 4);
    unsigned short* Pb     = (unsigned short*)carve((size_t)32 * 9216 * 2);

    hipMemsetAsync(ssq, 0, 2 * 4 * 768 * 4, stream);

    dim3 tb(32, 8);
    transpose_to_bf16<<<dim3(24, 24), tb, 0, stream>>>(Wq, WqT, 768, 768);
    transpose_to_bf16<<<dim3(48, 24), tb, 0, stream>>>(Wkv, WkvT, 768, 1536);
    transpose_to_bf16<<<dim3(24, 24), tb, 0, stream>>>(Wproj, WprojT, 768, 768);

    gemm_bt<true, false><<<dim3(6, 128), 256, 0, stream>>>(ctx, WqT, nullptr, Qb, 16384, 768, 768);
    gemm_bt<true, false><<<dim3(12, 128), 256, 0, stream>>>(dep, WkvT, nullptr, KVb, 16384, 1536, 768);

    col_ssq<<<dim3(3, 4, 8), 256, 0, stream>>>(Qb, ssq, 768);
    col_ssq<<<dim3(3, 4, 8), 256, 0, stream>>>(KVb, ssq + 3072, 1536);

    s_partial<<<dim3(8, 8, 4), 256, 0, stream>>>(Qb, KVb, Spart);
    softmax_k<<<32, 128, 0, stream>>>(Spart, ssq, Pb);
    pv_gemm<<<dim3(32, 32), 256, 0, stream>>>(KVb, Pb, Xb);
    gemm_bt<false, true><<<dim3(6, 128), 256, 0, stream>>>(Xb, WprojT, bproj, out, 16384, 768, 768);
}

// Round 2
// 434.943 us; speedup vs baseline: 1.0758x; 1.0758x over previous
//
#include <hip/hip_runtime.h>

// ---------------------------------------------------------------------------
// Channel attention (XCA-style): B=4, N=4096, C=768, H=8, HD=96, fp32 in/out.
// R2: bf16-only MFMA gemms with global_load_lds(16B) staging (m97 structure),
// XCD-aware block swizzle, fp32->bf16 conversion hoisted to a memory-bound
// prepass. Attention core unchanged from R1.
// ---------------------------------------------------------------------------

using bf16x8 = __attribute__((ext_vector_type(8))) short;
using f32x4  = __attribute__((ext_vector_type(4))) float;

#define SCALE_ 0.10206207261596575f   // 96^-0.5

__device__ __forceinline__ unsigned short f2bf(float f) {
    unsigned int u = __builtin_bit_cast(unsigned int, f);
    u += 0x7FFFu + ((u >> 16) & 1u);          // RNE, finite inputs only
    return (unsigned short)(u >> 16);
}
__device__ __forceinline__ float bf2f(unsigned short h) {
    unsigned int u = ((unsigned int)h) << 16;
    return __builtin_bit_cast(float, u);
}

__device__ __forceinline__ void glds16(const unsigned short* g, unsigned short* l) {
    __builtin_amdgcn_global_load_lds(
        (const __attribute__((address_space(1))) void*)g,
        (__attribute__((address_space(3))) void*)l, 16, 0, 0);
}

// ---------------------------------------------------------------------------
// fp32 -> bf16 bulk convert (memory-bound). 8 elems/thread.
// ---------------------------------------------------------------------------
__global__ void f32_to_bf16_k(const float* __restrict__ in,
                              unsigned short* __restrict__ out)
{
    size_t idx = ((size_t)blockIdx.x * 256 + threadIdx.x) * 8;
    float4 v0 = *(const float4*)&in[idx];
    float4 v1 = *(const float4*)&in[idx + 4];
    unsigned short h[8];
    h[0] = f2bf(v0.x); h[1] = f2bf(v0.y); h[2] = f2bf(v0.z); h[3] = f2bf(v0.w);
    h[4] = f2bf(v1.x); h[5] = f2bf(v1.y); h[6] = f2bf(v1.z); h[7] = f2bf(v1.w);
    *(bf16x8*)&out[idx] = *(bf16x8*)h;
}

// ---------------------------------------------------------------------------
// Weight transpose + fp32->bf16: W[K][N] -> Wt[N][K]. block(32,8).
// ---------------------------------------------------------------------------
__global__ void transpose_to_bf16(const float* __restrict__ W,
                                  unsigned short* __restrict__ Wt,
                                  int K, int N)
{
    __shared__ float tile[32][33];
    int n0 = blockIdx.x * 32, k0 = blockIdx.y * 32;
    int tx = threadIdx.x, ty = threadIdx.y;
    #pragma unroll
    for (int i = 0; i < 32; i += 8)
        tile[ty + i][tx] = W[(size_t)(k0 + ty + i) * N + n0 + tx];
    __syncthreads();
    #pragma unroll
    for (int i = 0; i < 32; i += 8)
        Wt[(size_t)(n0 + ty + i) * K + k0 + tx] = f2bf(tile[tx][ty + i]);
}

// ---------------------------------------------------------------------------
// GEMM: C[M][N] = A[M][K] * W[K][N], A bf16 row-major, W transposed bf16
// Bt[N][K]. 128x128 tile, BK=32, 4 waves x (64x64 via 4x4 16x16x32 MFMA).
// Staging: global_load_lds width=16, unpadded 128x32 LDS (lane*16 layout
// == row-major; ds_read_b128 frag reads are dense -> conflict-free).
// XCD swizzle: each XCD owns a contiguous band of Mt/8 m-tiles so A slices
// are fetched by exactly one XCD L2; full B (<=2.4MB) fits each L2.
// ---------------------------------------------------------------------------
template<bool OUT_F32_BIAS>
__global__ __launch_bounds__(256) void gemm_bt(
    const unsigned short* __restrict__ A, const unsigned short* __restrict__ Bt,
    const float* __restrict__ bias, void* __restrict__ Cv,
    int M, int N, int K)
{
    __shared__ unsigned short As[128 * 32];
    __shared__ unsigned short Bs[128 * 32];

    const int Nt = gridDim.x, Mt = gridDim.y;
    const int lin = blockIdx.y * Nt + blockIdx.x;
    const int xcd = lin & 7, li = lin >> 3;
    const int band = Mt >> 3;
    const int mt = xcd * band + (li % band);
    const int nt = li / band;
    const int bm = mt * 128, bn = nt * 128;

    const int t = threadIdx.x, lane = t & 63, w = t >> 6;
    const int wm = (w >> 1) * 64, wn = (w & 1) * 64;
    const int mf = lane & 15, k8 = (lane >> 4) * 8;

    // staging addresses: wave w stages rows [w*32, w*32+32) of each tile,
    // 16 rows per glds16 (4 lanes/row, 16B/lane, LDS offset = lane*16).
    const int srow = lane >> 2, scol = (lane & 3) * 8;
    const unsigned short* gA = A  + (size_t)(bm + w * 32 + srow) * K + scol;
    const unsigned short* gB = Bt + (size_t)(bn + w * 32 + srow) * K + scol;
    unsigned short* lA = &As[(w * 32) * 32];
    unsigned short* lB = &Bs[(w * 32) * 32];

    f32x4 acc[4][4] = {};

    for (int k0 = 0; k0 < K; k0 += 32) {
        glds16(gA + k0,          lA);
        glds16(gA + 16 * K + k0, lA + 16 * 32);
        glds16(gB + k0,          lB);
        glds16(gB + 16 * K + k0, lB + 16 * 32);
        __syncthreads();
        bf16x8 a[4], b[4];
        #pragma unroll
        for (int i = 0; i < 4; i++) a[i] = *(const bf16x8*)&As[(wm + i * 16 + mf) * 32 + k8];
        #pragma unroll
        for (int j = 0; j < 4; j++) b[j] = *(const bf16x8*)&Bs[(wn + j * 16 + mf) * 32 + k8];
        #pragma unroll
        for (int i = 0; i < 4; i++)
            #pragma unroll
            for (int j = 0; j < 4; j++)
                acc[i][j] = __builtin_amdgcn_mfma_f32_16x16x32_bf16(a[i], b[j], acc[i][j], 0, 0, 0);
        __syncthreads();
    }

    // C/D layout (m89-verified): col = lane&15, row = (lane>>4)*4 + r
    #pragma unroll
    for (int i = 0; i < 4; i++) {
        #pragma unroll
        for (int j = 0; j < 4; j++) {
            int col  = bn + wn + j * 16 + mf;
            int row0 = bm + wm + i * 16 + (lane >> 4) * 4;
            if constexpr (OUT_F32_BIAS) {
                float bv = bias[col];
                float* C = (float*)Cv;
                #pragma unroll
                for (int r = 0; r < 4; r++)
                    C[(size_t)(row0 + r) * N + col] = acc[i][j][r] + bv;
            } else {
                unsigned short* C = (unsigned short*)Cv;
                #pragma unroll
                for (int r = 0; r < 4; r++)
                    C[(size_t)(row0 + r) * N + col] = f2bf(acc[i][j][r]);
            }
        }
    }
}

// ---------------------------------------------------------------------------
// Column sum-of-squares over the token axis (for L2-normalize over N).
// ---------------------------------------------------------------------------
__global__ void col_ssq(const unsigned short* __restrict__ X,
                        float* __restrict__ out, int row_stride)
{
    int t = threadIdx.x;
    int c = blockIdx.x * 256 + t;
    int b = blockIdx.y, chunk = blockIdx.z;
    size_t base = ((size_t)b * 4096 + (size_t)chunk * 512) * row_stride + c;
    float s = 0.f;
    for (int n = 0; n < 512; n++) {
        float v = bf2f(X[base + (size_t)n * row_stride]);
        s += v * v;
    }
    atomicAdd(&out[b * 768 + c], s);
}

// ---------------------------------------------------------------------------
// Partial gram: S_part[b][h][chunk][96][96] over 512-token chunks. fp32 VALU.
// ---------------------------------------------------------------------------
__global__ __launch_bounds__(256) void s_partial(
    const unsigned short* __restrict__ Q, const unsigned short* __restrict__ KV,
    float* __restrict__ Spart)
{
    __shared__ float Qs[16][100];
    __shared__ float Ks[16][100];
    int chunk = blockIdx.x, h = blockIdx.y, b = blockIdx.z;
    int t = threadIdx.x;
    int d0 = (t >> 4) * 6, e0 = (t & 15) * 6;
    float acc[6][6] = {};
    size_t qbase = ((size_t)b * 4096 + (size_t)chunk * 512) * 768 + h * 96;
    size_t kbase = ((size_t)b * 4096 + (size_t)chunk * 512) * 1536 + h * 96;

    for (int n0 = 0; n0 < 512; n0 += 16) {
        #pragma unroll
        for (int i = 0; i < 6; i++) {
            int idx = t + 256 * i;              // 1536 = 16 rows x 96 cols
            int row = idx / 96, c = idx - row * 96;
            Qs[row][c] = bf2f(Q[qbase + (size_t)(n0 + row) * 768 + c]);
            Ks[row][c] = bf2f(KV[kbase + (size_t)(n0 + row) * 1536 + c]);
        }
        __syncthreads();
        #pragma unroll
        for (int n = 0; n < 16; n++) {
            float2 qa = *(const float2*)&Qs[n][d0];
            float2 qb = *(const float2*)&Qs[n][d0 + 2];
            float2 qc = *(const float2*)&Qs[n][d0 + 4];
            float2 ka = *(const float2*)&Ks[n][e0];
            float2 kb = *(const float2*)&Ks[n][e0 + 2];
            float2 kc = *(const float2*)&Ks[n][e0 + 4];
            float qv[6] = {qa.x, qa.y, qb.x, qb.y, qc.x, qc.y};
            float kv[6] = {ka.x, ka.y, kb.x, kb.y, kc.x, kc.y};
            #pragma unroll
            for (int i = 0; i < 6; i++)
                #pragma unroll
                for (int j = 0; j < 6; j++)
                    acc[i][j] += qv[i] * kv[j];
        }
        __syncthreads();
    }
    float* outp = Spart + ((size_t)((b * 8 + h) * 8 + chunk)) * 9216;
    #pragma unroll
    for (int i = 0; i < 6; i++)
        #pragma unroll
        for (int j = 0; j < 6; j++)
            outp[(d0 + i) * 96 + e0 + j] = acc[i][j];
}

// ---------------------------------------------------------------------------
// Reduce partials, apply SCALE and norm reciprocals, row-softmax, P bf16.
// ---------------------------------------------------------------------------
__global__ void softmax_k(const float* __restrict__ Spart,
                          const float* __restrict__ ssq,
                          unsigned short* __restrict__ P)
{
    __shared__ float Sf[96 * 97];
    __shared__ float qsl[96];
    __shared__ float ksl[96];
    int bh = blockIdx.x, t = threadIdx.x;
    int b = bh >> 3, h = bh & 7;
    if (t < 96) {
        float nq = sqrtf(ssq[b * 768 + h * 96 + t]);
        qsl[t] = 1.0f / fmaxf(nq, 1e-12f);
        float nk = sqrtf(ssq[3072 + b * 768 + h * 96 + t]);
        ksl[t] = 1.0f / fmaxf(nk, 1e-12f);
    }
    __syncthreads();
    for (int idx = t; idx < 9216; idx += 128) {
        float s = 0.f;
        #pragma unroll
        for (int ch = 0; ch < 8; ch++)
            s += Spart[((size_t)(bh * 8 + ch)) * 9216 + idx];
        int d = idx / 96, e = idx - d * 96;
        Sf[d * 97 + e] = s * SCALE_ * qsl[d] * ksl[e];
    }
    __syncthreads();
    if (t < 96) {
        int d = t;
        float m = -1e30f;
        for (int e = 0; e < 96; e++) m = fmaxf(m, Sf[d * 97 + e]);
        float ssum = 0.f;
        for (int e = 0; e < 96; e++) {
            float ex = expf(Sf[d * 97 + e] - m);
            Sf[d * 97 + e] = ex;
            ssum += ex;
        }
        float inv = 1.0f / ssum;
        for (int e = 0; e < 96; e++)
            P[(size_t)bh * 9216 + d * 96 + e] = f2bf(Sf[d * 97 + e] * inv);
    }
}

// ---------------------------------------------------------------------------
// x[n][d] = sum_e V[n][e] * P[d][e] per (b,h).
// ---------------------------------------------------------------------------
__global__ __launch_bounds__(256) void pv_gemm(
    const unsigned short* __restrict__ KV, const unsigned short* __restrict__ P,
    unsigned short* __restrict__ X)
{
    __shared__ unsigned short Ps[96][104];
    int ntile = blockIdx.x, bh = blockIdx.y;
    int b = bh >> 3, h = bh & 7;
    int t = threadIdx.x, lane = t & 63, w = t >> 6;

    const unsigned short* Pg = P + (size_t)bh * 9216;
    #pragma unroll
    for (int i = 0; i < 9; i++) {
        int idx4 = t + 256 * i;                 // 2304 ushort4 chunks
        int row = idx4 / 24, c4 = (idx4 - row * 24) * 4;
        *(ushort4*)&Ps[row][c4] = *(const ushort4*)&Pg[row * 96 + c4];
    }
    __syncthreads();

    const unsigned short* Vbase = KV + (size_t)b * 4096 * 1536 + 768 + h * 96;
    int mf = lane & 15, k8 = (lane >> 4) * 8;
    f32x4 acc[2][6] = {};
    #pragma unroll
    for (int k = 0; k < 3; k++) {
        bf16x8 a[2], bb[6];
        #pragma unroll
        for (int i = 0; i < 2; i++) {
            int row = ntile * 128 + w * 32 + i * 16 + mf;
            a[i] = *(const bf16x8*)&Vbase[(size_t)row * 1536 + k * 32 + k8];
        }
        #pragma unroll
        for (int j = 0; j < 6; j++)
            bb[j] = *(const bf16x8*)&Ps[j * 16 + mf][k * 32 + k8];
        #pragma unroll
        for (int i = 0; i < 2; i++)
            #pragma unroll
            for (int j = 0; j < 6; j++)
                acc[i][j] = __builtin_amdgcn_mfma_f32_16x16x32_bf16(a[i], bb[j], acc[i][j], 0, 0, 0);
    }
    #pragma unroll
    for (int i = 0; i < 2; i++)
        #pragma unroll
        for (int j = 0; j < 6; j++)
            #pragma unroll
            for (int r = 0; r < 4; r++) {
                int n_tok = ntile * 128 + w * 32 + i * 16 + (lane >> 4) * 4 + r;
                int c = h * 96 + j * 16 + mf;
                X[((size_t)b * 4096 + n_tok) * 768 + c] = f2bf(acc[i][j][r]);
            }
}

// ---------------------------------------------------------------------------
extern "C" void kernel_launch(void* const* d_in, const int* in_sizes, int n_in,
                              void* d_out, int out_size, void* d_ws, size_t ws_size,
                              hipStream_t stream)
{
    (void)in_sizes; (void)n_in; (void)out_size; (void)ws_size;
    const float* ctx   = (const float*)d_in[0];
    const float* dep   = (const float*)d_in[1];
    const float* Wq    = (const float*)d_in[2];
    const float* Wkv   = (const float*)d_in[3];
    const float* Wproj = (const float*)d_in[4];
    const float* bproj = (const float*)d_in[5];
    float* out = (float*)d_out;

    char* p = (char*)d_ws;
    auto carve = [&](size_t bytes) {
        char* r = p;
        p += (bytes + 255) & ~(size_t)255;
        return r;
    };
    unsigned short* WqT    = (unsigned short*)carve((size_t)768 * 768 * 2);
    unsigned short* WkvT   = (unsigned short*)carve((size_t)1536 * 768 * 2);
    unsigned short* WprojT = (unsigned short*)carve((size_t)768 * 768 * 2);
    unsigned short* Qb     = (unsigned short*)carve((size_t)16384 * 768 * 2);
    unsigned short* KVb    = (unsigned short*)carve((size_t)16384 * 1536 * 2);
    unsigned short* Xb     = (unsigned short*)carve((size_t)16384 * 768 * 2);
    float*          ssq    = (float*)carve((size_t)2 * 4 * 768 * 4);
    float*          Spart  = (float*)carve((size_t)32 * 8 * 9216 * 4);
    unsigned short* Pb     = (unsigned short*)carve((size_t)32 * 9216 * 2);
    unsigned short* depB   = (unsigned short*)carve((size_t)16384 * 768 * 2);
    // ctx-bf16 aliases Xb: Q-gemm consumes it before pv_gemm writes Xb.
    unsigned short* ctxB   = Xb;

    hipMemsetAsync(ssq, 0, 2 * 4 * 768 * 4, stream);

    f32_to_bf16_k<<<6144, 256, 0, stream>>>(ctx, ctxB);
    f32_to_bf16_k<<<6144, 256, 0, stream>>>(dep, depB);

    dim3 tb(32, 8);
    transpose_to_bf16<<<dim3(24, 24), tb, 0, stream>>>(Wq, WqT, 768, 768);
    transpose_to_bf16<<<dim3(48, 24), tb, 0, stream>>>(Wkv, WkvT, 768, 1536);
    transpose_to_bf16<<<dim3(24, 24), tb, 0, stream>>>(Wproj, WprojT, 768, 768);

    gemm_bt<false><<<dim3(6, 128), 256, 0, stream>>>(ctxB, WqT, nullptr, Qb, 16384, 768, 768);
    gemm_bt<false><<<dim3(12, 128), 256, 0, stream>>>(depB, WkvT, nullptr, KVb, 16384, 1536, 768);

    col_ssq<<<dim3(3, 4, 8), 256, 0, stream>>>(Qb, ssq, 768);
    col_ssq<<<dim3(3, 4, 8), 256, 0, stream>>>(KVb, ssq + 3072, 1536);

    s_partial<<<dim3(8, 8, 4), 256, 0, stream>>>(Qb, KVb, Spart);
    softmax_k<<<32, 128, 0, stream>>>(Spart, ssq, Pb);
    pv_gemm<<<dim3(32, 32), 256, 0, stream>>>(KVb, Pb, Xb);
    gemm_bt<true><<<dim3(6, 128), 256, 0, stream>>>(Xb, WprojT, bproj, out, 16384, 768, 768);
}

// Round 3
// 372.761 us; speedup vs baseline: 1.2552x; 1.1668x over previous
//
#include <hip/hip_runtime.h>

// ---------------------------------------------------------------------------
// Channel attention (XCA): B=4, N=4096, C=768, H=8, HD=96, fp32 in/out.
// R3: 256x128 gemm blocks with 128x64 wave tiles (F/B 32->42.7), fragment-
// order LDS layout (glds16 lane map row=lane&15 -> frag reads are sequential
// ds_read_b128, zero bank conflicts), and MFMA s_gemm with fused in-LDS
// transpose + ssq (replaces s_partial + col_ssq x2).
// ---------------------------------------------------------------------------

using bf16x8 = __attribute__((ext_vector_type(8))) short;
using f32x4  = __attribute__((ext_vector_type(4))) float;

#define SCALE_ 0.10206207261596575f   // 96^-0.5

__device__ __forceinline__ unsigned short f2bf(float f) {
    unsigned int u = __builtin_bit_cast(unsigned int, f);
    u += 0x7FFFu + ((u >> 16) & 1u);          // RNE, finite inputs only
    return (unsigned short)(u >> 16);
}
__device__ __forceinline__ float bf2f(unsigned short h) {
    unsigned int u = ((unsigned int)h) << 16;
    return __builtin_bit_cast(float, u);
}

__device__ __forceinline__ void glds16(const unsigned short* g, unsigned short* l) {
    __builtin_amdgcn_global_load_lds(
        (const __attribute__((address_space(1))) void*)g,
        (__attribute__((address_space(3))) void*)l, 16, 0, 0);
}

// ---------------------------------------------------------------------------
// fp32 -> bf16 bulk convert (memory-bound). 8 elems/thread.
// ---------------------------------------------------------------------------
__global__ void f32_to_bf16_k(const float* __restrict__ in,
                              unsigned short* __restrict__ out)
{
    size_t idx = ((size_t)blockIdx.x * 256 + threadIdx.x) * 8;
    float4 v0 = *(const float4*)&in[idx];
    float4 v1 = *(const float4*)&in[idx + 4];
    unsigned short h[8];
    h[0] = f2bf(v0.x); h[1] = f2bf(v0.y); h[2] = f2bf(v0.z); h[3] = f2bf(v0.w);
    h[4] = f2bf(v1.x); h[5] = f2bf(v1.y); h[6] = f2bf(v1.z); h[7] = f2bf(v1.w);
    *(bf16x8*)&out[idx] = *(bf16x8*)h;
}

// ---------------------------------------------------------------------------
// Weight transpose + fp32->bf16: W[K][N] -> Wt[N][K]. block(32,8).
// ---------------------------------------------------------------------------
__global__ void transpose_to_bf16(const float* __restrict__ W,
                                  unsigned short* __restrict__ Wt,
                                  int K, int N)
{
    __shared__ float tile[32][33];
    int n0 = blockIdx.x * 32, k0 = blockIdx.y * 32;
    int tx = threadIdx.x, ty = threadIdx.y;
    #pragma unroll
    for (int i = 0; i < 32; i += 8)
        tile[ty + i][tx] = W[(size_t)(k0 + ty + i) * N + n0 + tx];
    __syncthreads();
    #pragma unroll
    for (int i = 0; i < 32; i += 8)
        Wt[(size_t)(n0 + ty + i) * K + k0 + tx] = f2bf(tile[tx][ty + i]);
}

// ---------------------------------------------------------------------------
// GEMM: C[M][N] = A[M][K] * Bt[N][K]^T, bf16 in, 256x128 block, BK=32.
// 4 waves, each a 128x64 tile (8x4 of 16x16x32 MFMA).
// LDS is stored in FRAGMENT ORDER: glds16 with lane map (row=lane&15,
// kchunk=lane>>4) gives 1KB blocks [kchunk][row16][16B]; the MFMA frag read
// is then As + block*512 + lane*8 -- sequential, zero bank conflicts.
// Global pattern per glds16: 16 rows x 64B contiguous (same as row-major).
// XCD swizzle: contiguous m-bands per XCD; B slice stays hot in each L2.
// ---------------------------------------------------------------------------
template<bool OUT_F32_BIAS>
__global__ __launch_bounds__(256, 2) void gemm_bt(
    const unsigned short* __restrict__ A, const unsigned short* __restrict__ Bt,
    const float* __restrict__ bias, void* __restrict__ Cv,
    int M, int N, int K)
{
    __shared__ unsigned short As[256 * 32];   // 16 blocks of 1KB
    __shared__ unsigned short Bs[128 * 32];   // 8 blocks of 1KB

    const int Nt = gridDim.x, Mt = gridDim.y;
    const int lin = blockIdx.y * Nt + blockIdx.x;
    const int xcd = lin & 7, li = lin >> 3;
    const int band = Mt >> 3;
    const int mt = xcd * band + (li % band);
    const int nt = li / band;
    const int bm = mt * 256, bn = nt * 128;

    const int t = threadIdx.x, lane = t & 63, w = t >> 6;
    const int wm = (w >> 1) * 128, wn = (w & 1) * 64;

    // staging lane map: row = lane&15, k-offset = (lane>>4)*8
    const int srow = lane & 15, skc = (lane >> 4) * 8;
    const unsigned short* gA = A  + (size_t)(bm + srow) * K + skc;
    const unsigned short* gB = Bt + (size_t)(bn + srow) * K + skc;

    f32x4 acc[8][4] = {};

    for (int k0 = 0; k0 < K; k0 += 32) {
        // wave w stages A blocks w*4..w*4+3 (rows w*64..w*64+63), B blocks w*2..w*2+1
        #pragma unroll
        for (int c = 0; c < 4; c++)
            glds16(gA + (size_t)(w * 64 + c * 16) * K + k0, &As[(w * 4 + c) * 512]);
        #pragma unroll
        for (int c = 0; c < 2; c++)
            glds16(gB + (size_t)(w * 32 + c * 16) * K + k0, &Bs[(w * 2 + c) * 512]);
        __syncthreads();
        bf16x8 a[8], b[4];
        #pragma unroll
        for (int i = 0; i < 8; i++)
            a[i] = *(const bf16x8*)&As[((wm >> 4) + i) * 512 + lane * 8];
        #pragma unroll
        for (int j = 0; j < 4; j++)
            b[j] = *(const bf16x8*)&Bs[((wn >> 4) + j) * 512 + lane * 8];
        #pragma unroll
        for (int i = 0; i < 8; i++)
            #pragma unroll
            for (int j = 0; j < 4; j++)
                acc[i][j] = __builtin_amdgcn_mfma_f32_16x16x32_bf16(a[i], b[j], acc[i][j], 0, 0, 0);
        __syncthreads();
    }

    // C/D layout: col = lane&15, row = (lane>>4)*4 + r
    const int mf = lane & 15;
    #pragma unroll
    for (int i = 0; i < 8; i++) {
        #pragma unroll
        for (int j = 0; j < 4; j++) {
            int col  = bn + wn + j * 16 + mf;
            int row0 = bm + wm + i * 16 + (lane >> 4) * 4;
            if constexpr (OUT_F32_BIAS) {
                float bv = bias[col];
                float* C = (float*)Cv;
                #pragma unroll
                for (int r = 0; r < 4; r++)
                    C[(size_t)(row0 + r) * N + col] = acc[i][j][r] + bv;
            } else {
                unsigned short* C = (unsigned short*)Cv;
                #pragma unroll
                for (int r = 0; r < 4; r++)
                    C[(size_t)(row0 + r) * N + col] = f2bf(acc[i][j][r]);
            }
        }
    }
}

// ---------------------------------------------------------------------------
// S-gram via MFMA with fused in-LDS transpose and ssq reduction.
// Per (split s, bh): S_part[bh][s][96][96] = sum over tokens [s*512,(s+1)*512)
// of Q[n][d]*K[n][e]. Stages 64-token chunks into transposed padded LDS
// ([d][n], stride 72 -> bank-balanced b128 frag reads), 4 waves as 2x2 of
// 48x48 (3x3 MFMA tiles, BK=64 = 2 ksteps). ssq partials accumulated from
// staged LDS (free HBM-wise), atomicAdd at end.
// ---------------------------------------------------------------------------
__global__ __launch_bounds__(256) void s_gemm(
    const unsigned short* __restrict__ Q, const unsigned short* __restrict__ KV,
    float* __restrict__ Spart, float* __restrict__ ssq)
{
    __shared__ unsigned short Qs[96 * 72];
    __shared__ unsigned short Ks[96 * 72];
    const int s = blockIdx.x, bh = blockIdx.y;
    const int b = bh >> 3, h = bh & 7;
    const int t = threadIdx.x, lane = t & 63, w = t >> 6;
    const int m0 = (w >> 1) * 48, n0 = (w & 1) * 48;
    const int mf = lane & 15, quad = lane >> 4;

    const size_t qbase = ((size_t)b * 4096 + (size_t)s * 512) * 768 + h * 96;
    const size_t kbase = ((size_t)b * 4096 + (size_t)s * 512) * 1536 + h * 96;

    f32x4 acc[3][3] = {};
    float ssq_acc = 0.f;

    for (int it = 0; it < 8; it++) {          // 8 chunks of 64 tokens
        // stage + transpose: 64 rows x 96 cols -> LDS [96][72]
        #pragma unroll
        for (int i = 0; i < 6; i++) {
            int idx = t + 256 * i;            // 1536 ushort4 units per operand
            int row = idx / 24, c4 = (idx - row * 24) * 4;
            ushort4 q4 = *(const ushort4*)&Q[qbase + (size_t)(it * 64 + row) * 768 + c4];
            ushort4 k4 = *(const ushort4*)&KV[kbase + (size_t)(it * 64 + row) * 1536 + c4];
            Qs[(c4 + 0) * 72 + row] = q4.x; Qs[(c4 + 1) * 72 + row] = q4.y;
            Qs[(c4 + 2) * 72 + row] = q4.z; Qs[(c4 + 3) * 72 + row] = q4.w;
            Ks[(c4 + 0) * 72 + row] = k4.x; Ks[(c4 + 1) * 72 + row] = k4.y;
            Ks[(c4 + 2) * 72 + row] = k4.z; Ks[(c4 + 3) * 72 + row] = k4.w;
        }
        __syncthreads();
        // fused ssq partials from staged data (t<96: Q row t; 96<=t<192: K row t-96)
        if (t < 96) {
            for (int n = 0; n < 64; n++) {
                float v = bf2f(Qs[t * 72 + n]);
                ssq_acc += v * v;
            }
        } else if (t < 192) {
            for (int n = 0; n < 64; n++) {
                float v = bf2f(Ks[(t - 96) * 72 + n]);
                ssq_acc += v * v;
            }
        }
        // MFMA: 3x3 tiles x 2 ksteps
        #pragma unroll
        for (int kk = 0; kk < 2; kk++) {
            bf16x8 a[3], bb[3];
            #pragma unroll
            for (int i = 0; i < 3; i++)
                a[i] = *(const bf16x8*)&Qs[(m0 + i * 16 + mf) * 72 + kk * 32 + quad * 8];
            #pragma unroll
            for (int j = 0; j < 3; j++)
                bb[j] = *(const bf16x8*)&Ks[(n0 + j * 16 + mf) * 72 + kk * 32 + quad * 8];
            #pragma unroll
            for (int i = 0; i < 3; i++)
                #pragma unroll
                for (int j = 0; j < 3; j++)
                    acc[i][j] = __builtin_amdgcn_mfma_f32_16x16x32_bf16(a[i], bb[j], acc[i][j], 0, 0, 0);
        }
        __syncthreads();
    }

    if (t < 96)
        atomicAdd(&ssq[b * 768 + h * 96 + t], ssq_acc);
    else if (t < 192)
        atomicAdd(&ssq[3072 + b * 768 + h * 96 + (t - 96)], ssq_acc);

    float* outp = Spart + ((size_t)(bh * 8 + s)) * 9216;
    #pragma unroll
    for (int i = 0; i < 3; i++)
        #pragma unroll
        for (int j = 0; j < 3; j++) {
            int e = n0 + j * 16 + mf;
            int d0 = m0 + i * 16 + quad * 4;
            #pragma unroll
            for (int r = 0; r < 4; r++)
                outp[(d0 + r) * 96 + e] = acc[i][j][r];
        }
}

// ---------------------------------------------------------------------------
// Reduce partials, apply SCALE and norm reciprocals, row-softmax, P bf16.
// ---------------------------------------------------------------------------
__global__ void softmax_k(const float* __restrict__ Spart,
                          const float* __restrict__ ssq,
                          unsigned short* __restrict__ P)
{
    __shared__ float Sf[96 * 97];
    __shared__ float qsl[96];
    __shared__ float ksl[96];
    int bh = blockIdx.x, t = threadIdx.x;
    int b = bh >> 3, h = bh & 7;
    if (t < 96) {
        float nq = sqrtf(ssq[b * 768 + h * 96 + t]);
        qsl[t] = 1.0f / fmaxf(nq, 1e-12f);
        float nk = sqrtf(ssq[3072 + b * 768 + h * 96 + t]);
        ksl[t] = 1.0f / fmaxf(nk, 1e-12f);
    }
    __syncthreads();
    for (int idx = t; idx < 9216; idx += 128) {
        float s = 0.f;
        #pragma unroll
        for (int ch = 0; ch < 8; ch++)
            s += Spart[((size_t)(bh * 8 + ch)) * 9216 + idx];
        int d = idx / 96, e = idx - d * 96;
        Sf[d * 97 + e] = s * SCALE_ * qsl[d] * ksl[e];
    }
    __syncthreads();
    if (t < 96) {
        int d = t;
        float m = -1e30f;
        for (int e = 0; e < 96; e++) m = fmaxf(m, Sf[d * 97 + e]);
        float ssum = 0.f;
        for (int e = 0; e < 96; e++) {
            float ex = expf(Sf[d * 97 + e] - m);
            Sf[d * 97 + e] = ex;
            ssum += ex;
        }
        float inv = 1.0f / ssum;
        for (int e = 0; e < 96; e++)
            P[(size_t)bh * 9216 + d * 96 + e] = f2bf(Sf[d * 97 + e] * inv);
    }
}

// ---------------------------------------------------------------------------
// x[n][d] = sum_e V[n][e] * P[d][e] per (b,h).
// ---------------------------------------------------------------------------
__global__ __launch_bounds__(256) void pv_gemm(
    const unsigned short* __restrict__ KV, const unsigned short* __restrict__ P,
    unsigned short* __restrict__ X)
{
    __shared__ unsigned short Ps[96][104];
    int ntile = blockIdx.x, bh = blockIdx.y;
    int b = bh >> 3, h = bh & 7;
    int t = threadIdx.x, lane = t & 63, w = t >> 6;

    const unsigned short* Pg = P + (size_t)bh * 9216;
    #pragma unroll
    for (int i = 0; i < 9; i++) {
        int idx4 = t + 256 * i;                 // 2304 ushort4 chunks
        int row = idx4 / 24, c4 = (idx4 - row * 24) * 4;
        *(ushort4*)&Ps[row][c4] = *(const ushort4*)&Pg[row * 96 + c4];
    }
    __syncthreads();

    const unsigned short* Vbase = KV + (size_t)b * 4096 * 1536 + 768 + h * 96;
    int mf = lane & 15, k8 = (lane >> 4) * 8;
    f32x4 acc[2][6] = {};
    #pragma unroll
    for (int k = 0; k < 3; k++) {
        bf16x8 a[2], bb[6];
        #pragma unroll
        for (int i = 0; i < 2; i++) {
            int row = ntile * 128 + w * 32 + i * 16 + mf;
            a[i] = *(const bf16x8*)&Vbase[(size_t)row * 1536 + k * 32 + k8];
        }
        #pragma unroll
        for (int j = 0; j < 6; j++)
            bb[j] = *(const bf16x8*)&Ps[j * 16 + mf][k * 32 + k8];
        #pragma unroll
        for (int i = 0; i < 2; i++)
            #pragma unroll
            for (int j = 0; j < 6; j++)
                acc[i][j] = __builtin_amdgcn_mfma_f32_16x16x32_bf16(a[i], bb[j], acc[i][j], 0, 0, 0);
    }
    #pragma unroll
    for (int i = 0; i < 2; i++)
        #pragma unroll
        for (int j = 0; j < 6; j++)
            #pragma unroll
            for (int r = 0; r < 4; r++) {
                int n_tok = ntile * 128 + w * 32 + i * 16 + (lane >> 4) * 4 + r;
                int c = h * 96 + j * 16 + mf;
                X[((size_t)b * 4096 + n_tok) * 768 + c] = f2bf(acc[i][j][r]);
            }
}

// ---------------------------------------------------------------------------
extern "C" void kernel_launch(void* const* d_in, const int* in_sizes, int n_in,
                              void* d_out, int out_size, void* d_ws, size_t ws_size,
                              hipStream_t stream)
{
    (void)in_sizes; (void)n_in; (void)out_size; (void)ws_size;
    const float* ctx   = (const float*)d_in[0];
    const float* dep   = (const float*)d_in[1];
    const float* Wq    = (const float*)d_in[2];
    const float* Wkv   = (const float*)d_in[3];
    const float* Wproj = (const float*)d_in[4];
    const float* bproj = (const float*)d_in[5];
    float* out = (float*)d_out;

    char* p = (char*)d_ws;
    auto carve = [&](size_t bytes) {
        char* r = p;
        p += (bytes + 255) & ~(size_t)255;
        return r;
    };
    unsigned short* WqT    = (unsigned short*)carve((size_t)768 * 768 * 2);
    unsigned short* WkvT   = (unsigned short*)carve((size_t)1536 * 768 * 2);
    unsigned short* WprojT = (unsigned short*)carve((size_t)768 * 768 * 2);
    unsigned short* Qb     = (unsigned short*)carve((size_t)16384 * 768 * 2);
    unsigned short* KVb    = (unsigned short*)carve((size_t)16384 * 1536 * 2);
    unsigned short* Xb     = (unsigned short*)carve((size_t)16384 * 768 * 2);
    float*          ssq    = (float*)carve((size_t)2 * 4 * 768 * 4);
    float*          Spart  = (float*)carve((size_t)32 * 8 * 9216 * 4);
    unsigned short* Pb     = (unsigned short*)carve((size_t)32 * 9216 * 2);
    unsigned short* depB   = (unsigned short*)carve((size_t)16384 * 768 * 2);
    // ctx-bf16 aliases Xb: Q-gemm consumes it before pv_gemm writes Xb.
    unsigned short* ctxB   = Xb;

    hipMemsetAsync(ssq, 0, 2 * 4 * 768 * 4, stream);

    f32_to_bf16_k<<<6144, 256, 0, stream>>>(ctx, ctxB);
    f32_to_bf16_k<<<6144, 256, 0, stream>>>(dep, depB);

    dim3 tb(32, 8);
    transpose_to_bf16<<<dim3(24, 24), tb, 0, stream>>>(Wq, WqT, 768, 768);
    transpose_to_bf16<<<dim3(48, 24), tb, 0, stream>>>(Wkv, WkvT, 768, 1536);
    transpose_to_bf16<<<dim3(24, 24), tb, 0, stream>>>(Wproj, WprojT, 768, 768);

    gemm_bt<false><<<dim3(6, 64), 256, 0, stream>>>(ctxB, WqT, nullptr, Qb, 16384, 768, 768);
    gemm_bt<false><<<dim3(12, 64), 256, 0, stream>>>(depB, WkvT, nullptr, KVb, 16384, 1536, 768);

    s_gemm<<<dim3(8, 32), 256, 0, stream>>>(Qb, KVb, Spart, ssq);
    softmax_k<<<32, 128, 0, stream>>>(Spart, ssq, Pb);
    pv_gemm<<<dim3(32, 32), 256, 0, stream>>>(KVb, Pb, Xb);
    gemm_bt<true><<<dim3(6, 64), 256, 0, stream>>>(Xb, WprojT, bproj, out, 16384, 768, 768);
}

// Round 4
// 367.791 us; speedup vs baseline: 1.2722x; 1.0135x over previous
//
#include <hip/hip_runtime.h>

// ---------------------------------------------------------------------------
// Channel attention (XCA): B=4, N=4096, C=768, H=8, HD=96, fp32 in/out.
// R4: 128x128 gemm tiles (3 blocks/CU) + fragment-order LDS + single-barrier
// double-buffered K-loop. Q/KV gemm epilogues write Qt/Kt TRANSPOSED
// [bh][d][n] (contiguous ushort4 in n) so s_gemm needs no LDS transpose;
// ssq fused into s_gemm from register fragments. V compacted to Vb[n][768].
// ---------------------------------------------------------------------------

using bf16x8 = __attribute__((ext_vector_type(8))) short;
using f32x4  = __attribute__((ext_vector_type(4))) float;

#define SCALE_ 0.10206207261596575f   // 96^-0.5

__device__ __forceinline__ unsigned short f2bf(float f) {
    unsigned int u = __builtin_bit_cast(unsigned int, f);
    u += 0x7FFFu + ((u >> 16) & 1u);          // RNE, finite inputs only
    return (unsigned short)(u >> 16);
}
__device__ __forceinline__ float bf2f(unsigned short h) {
    unsigned int u = ((unsigned int)h) << 16;
    return __builtin_bit_cast(float, u);
}

__device__ __forceinline__ void glds16(const unsigned short* g, unsigned short* l) {
    __builtin_amdgcn_global_load_lds(
        (const __attribute__((address_space(1))) void*)g,
        (__attribute__((address_space(3))) void*)l, 16, 0, 0);
}

// sum of squares of 8 bf16 packed in a frag
__device__ __forceinline__ float ssq8(bf16x8 v) {
    uint4 u = __builtin_bit_cast(uint4, v);
    unsigned a[4] = {u.x, u.y, u.z, u.w};
    float s = 0.f;
    #pragma unroll
    for (int i = 0; i < 4; i++) {
        float lo = __builtin_bit_cast(float, a[i] << 16);
        float hi = __builtin_bit_cast(float, a[i] & 0xFFFF0000u);
        s += lo * lo + hi * hi;
    }
    return s;
}

// ---------------------------------------------------------------------------
// fp32 -> bf16 bulk convert (memory-bound). 8 elems/thread.
// ---------------------------------------------------------------------------
__global__ void f32_to_bf16_k(const float* __restrict__ in,
                              unsigned short* __restrict__ out)
{
    size_t idx = ((size_t)blockIdx.x * 256 + threadIdx.x) * 8;
    float4 v0 = *(const float4*)&in[idx];
    float4 v1 = *(const float4*)&in[idx + 4];
    unsigned short h[8];
    h[0] = f2bf(v0.x); h[1] = f2bf(v0.y); h[2] = f2bf(v0.z); h[3] = f2bf(v0.w);
    h[4] = f2bf(v1.x); h[5] = f2bf(v1.y); h[6] = f2bf(v1.z); h[7] = f2bf(v1.w);
    *(bf16x8*)&out[idx] = *(bf16x8*)h;
}

// ---------------------------------------------------------------------------
// Weight transpose + fp32->bf16: W[K][N] -> Wt[N][K]. block(32,8).
// ---------------------------------------------------------------------------
__global__ void transpose_to_bf16(const float* __restrict__ W,
                                  unsigned short* __restrict__ Wt,
                                  int K, int N)
{
    __shared__ float tile[32][33];
    int n0 = blockIdx.x * 32, k0 = blockIdx.y * 32;
    int tx = threadIdx.x, ty = threadIdx.y;
    #pragma unroll
    for (int i = 0; i < 32; i += 8)
        tile[ty + i][tx] = W[(size_t)(k0 + ty + i) * N + n0 + tx];
    __syncthreads();
    #pragma unroll
    for (int i = 0; i < 32; i += 8)
        Wt[(size_t)(n0 + ty + i) * K + k0 + tx] = f2bf(tile[tx][ty + i]);
}

// ---------------------------------------------------------------------------
// GEMM: C = A[M][K] * Bt[N][K]^T, bf16. 128x128 block, BK=32, 4 waves 2x2
// of 64x64 (4x4 16x16x32 MFMA). Fragment-order LDS (conflict-free b128),
// single-barrier double-buffered K-loop: barrier -> prefetch(next buf) ->
// ds_read+MFMA(cur buf). vmcnt(0)-at-barrier drains a prefetch that had a
// full iteration in flight. ~130 regs -> 3 blocks/CU; LDS 32KB.
// MODE 0: write transposed bf16 Qt[bh][d][n]     (out0)
// MODE 1: cols<768 -> Kt[bh][d][n] (out0); cols>=768 -> Vb[m][768] (out1)
// MODE 2: fp32 + bias row-major (out0)
// ---------------------------------------------------------------------------
template<int MODE>
__global__ __launch_bounds__(256) void gemm_bt(
    const unsigned short* __restrict__ A, const unsigned short* __restrict__ Bt,
    const float* __restrict__ bias, void* __restrict__ out0, void* __restrict__ out1,
    int M, int N, int K)
{
    __shared__ unsigned short As[2][128 * 32];
    __shared__ unsigned short Bs[2][128 * 32];

    const int Nt = gridDim.x, Mt = gridDim.y;
    const int lin = blockIdx.y * Nt + blockIdx.x;
    const int xcd = lin & 7, li = lin >> 3;
    const int band = Mt >> 3;
    const int mt = xcd * band + (li % band);
    const int nt = li / band;
    const int bm = mt * 128, bn = nt * 128;

    const int t = threadIdx.x, lane = t & 63, w = t >> 6;
    const int wm = (w >> 1) * 64, wn = (w & 1) * 64;
    const int mf = lane & 15, quad = lane >> 4;

    // staging lane map (fragment order): row = lane&15, k-off = (lane>>4)*8
    const int srow = lane & 15, skc = (lane >> 4) * 8;
    const unsigned short* gA = A  + (size_t)(bm + w * 32 + srow) * K + skc;
    const unsigned short* gB = Bt + (size_t)(bn + w * 32 + srow) * K + skc;

    f32x4 acc[4][4] = {};

    // prologue: stage k-tile 0 into buffer 0 (wave w owns 16-row groups w*2, w*2+1)
    #pragma unroll
    for (int c = 0; c < 2; c++) {
        glds16(gA + (size_t)(c * 16) * K, &As[0][(w * 2 + c) * 512]);
        glds16(gB + (size_t)(c * 16) * K, &Bs[0][(w * 2 + c) * 512]);
    }

    const int KI = K >> 5;
    for (int ki = 0; ki < KI; ki++) {
        const int cur = ki & 1;
        __syncthreads();                       // drains prefetch into cur + reads of cur^1
        if (ki + 1 < KI) {
            const int nxt = cur ^ 1;
            const int k0 = (ki + 1) * 32;
            #pragma unroll
            for (int c = 0; c < 2; c++) {
                glds16(gA + (size_t)(c * 16) * K + k0, &As[nxt][(w * 2 + c) * 512]);
                glds16(gB + (size_t)(c * 16) * K + k0, &Bs[nxt][(w * 2 + c) * 512]);
            }
        }
        bf16x8 a[4], b[4];
        #pragma unroll
        for (int i = 0; i < 4; i++)
            a[i] = *(const bf16x8*)&As[cur][(((w >> 1) * 4) + i) * 512 + lane * 8];
        #pragma unroll
        for (int j = 0; j < 4; j++)
            b[j] = *(const bf16x8*)&Bs[cur][(((w & 1) * 4) + j) * 512 + lane * 8];
        #pragma unroll
        for (int i = 0; i < 4; i++)
            #pragma unroll
            for (int j = 0; j < 4; j++)
                acc[i][j] = __builtin_amdgcn_mfma_f32_16x16x32_bf16(a[i], b[j], acc[i][j], 0, 0, 0);
    }

    // C/D layout: col = lane&15, row = quad*4 + r
    if constexpr (MODE == 2) {
        float* C = (float*)out0;
        #pragma unroll
        for (int i = 0; i < 4; i++) {
            int row0 = bm + wm + i * 16 + quad * 4;
            #pragma unroll
            for (int j = 0; j < 4; j++) {
                int col = bn + wn + j * 16 + mf;
                float bv = bias[col];
                #pragma unroll
                for (int r = 0; r < 4; r++)
                    C[(size_t)(row0 + r) * N + col] = acc[i][j][r] + bv;
            }
        }
    } else {
        unsigned short* Tr = (unsigned short*)out0;   // Qt or Kt [bh][96][4096]
        unsigned short* Vb = (unsigned short*)out1;   // [16384][768]
        const bool kpart = (MODE == 0) || (bn < 768);
        #pragma unroll
        for (int i = 0; i < 4; i++) {
            int row0 = bm + wm + i * 16 + quad * 4;   // global token index
            int bb = row0 >> 12, n = row0 & 4095;
            #pragma unroll
            for (int j = 0; j < 4; j++) {
                int c = bn + wn + j * 16 + mf;
                if (kpart) {
                    int h = (c * 683) >> 16;          // floor(c/96) for c<768
                    int d = c - h * 96;
                    size_t o = ((size_t)((bb * 8 + h) * 96 + d)) * 4096 + n;
                    ushort4 v4;
                    v4.x = f2bf(acc[i][j][0]); v4.y = f2bf(acc[i][j][1]);
                    v4.z = f2bf(acc[i][j][2]); v4.w = f2bf(acc[i][j][3]);
                    *(ushort4*)&Tr[o] = v4;
                } else {
                    int cv = c - 768;
                    #pragma unroll
                    for (int r = 0; r < 4; r++)
                        Vb[(size_t)(row0 + r) * 768 + cv] = f2bf(acc[i][j][r]);
                }
            }
        }
    }
}

// ---------------------------------------------------------------------------
// S-gram: Spart[bh][s][96][96] = sum over n-window of Qt[d][n]*Kt[e][n].
// Operands are n-contiguous -> glds16 fragment-order staging, no transpose.
// 4 waves 2x2 of 48x48 (3x3 MFMA), BK=64 (2 ksteps/iter), 4 iters of 64 n,
// single-barrier dbuf. ssq fused from register frags (dedup by wave parity,
// quad shuffle-reduce, atomicAdd). grid(16 splits, 32 bh).
// ---------------------------------------------------------------------------
__global__ __launch_bounds__(256) void s_gemm(
    const unsigned short* __restrict__ Qt, const unsigned short* __restrict__ Kt,
    float* __restrict__ Spart, float* __restrict__ ssq)
{
    __shared__ unsigned short Qs[2][12 * 512];
    __shared__ unsigned short Ks[2][12 * 512];
    const int s = blockIdx.x, bh = blockIdx.y;
    const int t = threadIdx.x, lane = t & 63, w = t >> 6;
    const int m0 = (w >> 1) * 48, n0w = (w & 1) * 48;
    const int mf = lane & 15, quad = lane >> 4;
    const int srow = lane & 15, skc = (lane >> 4) * 8;
    const int nwin = s * 256;

    const unsigned short* Qg = Qt + (size_t)bh * 96 * 4096;
    const unsigned short* Kg = Kt + (size_t)bh * 96 * 4096;

    f32x4 acc[3][3] = {};
    float sq[3] = {0.f, 0.f, 0.f}, sk[3] = {0.f, 0.f, 0.f};

    // prologue: wave w stages blocks w*3..w*3+2 per operand (bi = kc*6+g)
    #pragma unroll
    for (int c = 0; c < 3; c++) {
        int bi = w * 3 + c, kc = bi / 6, g = bi % 6;
        size_t go = (size_t)(g * 16 + srow) * 4096 + nwin + kc * 32 + skc;
        glds16(Qg + go, &Qs[0][bi * 512]);
        glds16(Kg + go, &Ks[0][bi * 512]);
    }

    for (int it = 0; it < 4; it++) {
        const int cur = it & 1;
        __syncthreads();
        if (it + 1 < 4) {
            const int nxt = cur ^ 1;
            const int nn = nwin + (it + 1) * 64;
            #pragma unroll
            for (int c = 0; c < 3; c++) {
                int bi = w * 3 + c, kc = bi / 6, g = bi % 6;
                size_t go = (size_t)(g * 16 + srow) * 4096 + nn + kc * 32 + skc;
                glds16(Qg + go, &Qs[nxt][bi * 512]);
                glds16(Kg + go, &Ks[nxt][bi * 512]);
            }
        }
        #pragma unroll
        for (int kk = 0; kk < 2; kk++) {
            bf16x8 a[3], b[3];
            #pragma unroll
            for (int i = 0; i < 3; i++)
                a[i] = *(const bf16x8*)&Qs[cur][(kk * 6 + (w >> 1) * 3 + i) * 512 + lane * 8];
            #pragma unroll
            for (int j = 0; j < 3; j++)
                b[j] = *(const bf16x8*)&Ks[cur][(kk * 6 + (w & 1) * 3 + j) * 512 + lane * 8];
            if ((w & 1) == 0) {                 // waves 0,2: Q rows m0..m0+47 (unique)
                #pragma unroll
                for (int i = 0; i < 3; i++) sq[i] += ssq8(a[i]);
            }
            if ((w >> 1) == 0) {                // waves 0,1: K rows n0w..n0w+47 (unique)
                #pragma unroll
                for (int j = 0; j < 3; j++) sk[j] += ssq8(b[j]);
            }
            #pragma unroll
            for (int i = 0; i < 3; i++)
                #pragma unroll
                for (int j = 0; j < 3; j++)
                    acc[i][j] = __builtin_amdgcn_mfma_f32_16x16x32_bf16(a[i], b[j], acc[i][j], 0, 0, 0);
        }
    }

    // ssq: quads hold disjoint n-chunks -> reduce across quads, lane<16 commits
    if ((w & 1) == 0) {
        #pragma unroll
        for (int i = 0; i < 3; i++) {
            float v = sq[i];
            v += __shfl_xor(v, 16, 64);
            v += __shfl_xor(v, 32, 64);
            if (lane < 16) atomicAdd(&ssq[bh * 96 + m0 + i * 16 + lane], v);
        }
    }
    if ((w >> 1) == 0) {
        #pragma unroll
        for (int j = 0; j < 3; j++) {
            float v = sk[j];
            v += __shfl_xor(v, 16, 64);
            v += __shfl_xor(v, 32, 64);
            if (lane < 16) atomicAdd(&ssq[3072 + bh * 96 + n0w + j * 16 + lane], v);
        }
    }

    float* outp = Spart + (size_t)(bh * 16 + s) * 9216;
    #pragma unroll
    for (int i = 0; i < 3; i++)
        #pragma unroll
        for (int j = 0; j < 3; j++) {
            int e  = n0w + j * 16 + mf;
            int d0 = m0 + i * 16 + quad * 4;
            #pragma unroll
            for (int r = 0; r < 4; r++)
                outp[(d0 + r) * 96 + e] = acc[i][j][r];
        }
}

// ---------------------------------------------------------------------------
// Reduce 16 partials, apply SCALE and norm reciprocals, row-softmax, P bf16.
// ---------------------------------------------------------------------------
__global__ void softmax_k(const float* __restrict__ Spart,
                          const float* __restrict__ ssq,
                          unsigned short* __restrict__ P)
{
    __shared__ float Sf[96 * 97];
    __shared__ float qsl[96];
    __shared__ float ksl[96];
    int bh = blockIdx.x, t = threadIdx.x;
    if (t < 96) {
        float nq = sqrtf(ssq[bh * 96 + t]);
        qsl[t] = 1.0f / fmaxf(nq, 1e-12f);
        float nk = sqrtf(ssq[3072 + bh * 96 + t]);
        ksl[t] = 1.0f / fmaxf(nk, 1e-12f);
    }
    __syncthreads();
    for (int idx = t; idx < 9216; idx += 128) {
        float sv = 0.f;
        #pragma unroll
        for (int ch = 0; ch < 16; ch++)
            sv += Spart[(size_t)(bh * 16 + ch) * 9216 + idx];
        int d = idx / 96, e = idx - d * 96;
        Sf[d * 97 + e] = sv * SCALE_ * qsl[d] * ksl[e];
    }
    __syncthreads();
    if (t < 96) {
        int d = t;
        float m = -1e30f;
        for (int e = 0; e < 96; e++) m = fmaxf(m, Sf[d * 97 + e]);
        float ssum = 0.f;
        for (int e = 0; e < 96; e++) {
            float ex = expf(Sf[d * 97 + e] - m);
            Sf[d * 97 + e] = ex;
            ssum += ex;
        }
        float inv = 1.0f / ssum;
        for (int e = 0; e < 96; e++)
            P[(size_t)bh * 9216 + d * 96 + e] = f2bf(Sf[d * 97 + e] * inv);
    }
}

// ---------------------------------------------------------------------------
// x[n][d] = sum_e V[n][e] * P[d][e] per (b,h). V from compact Vb[m][768].
// ---------------------------------------------------------------------------
__global__ __launch_bounds__(256) void pv_gemm(
    const unsigned short* __restrict__ Vb, const unsigned short* __restrict__ P,
    unsigned short* __restrict__ X)
{
    __shared__ unsigned short Ps[96][104];
    int ntile = blockIdx.x, bh = blockIdx.y;
    int b = bh >> 3, h = bh & 7;
    int t = threadIdx.x, lane = t & 63, w = t >> 6;

    const unsigned short* Pg = P + (size_t)bh * 9216;
    #pragma unroll
    for (int i = 0; i < 9; i++) {
        int idx4 = t + 256 * i;                 // 2304 ushort4 chunks
        int row = idx4 / 24, c4 = (idx4 - row * 24) * 4;
        *(ushort4*)&Ps[row][c4] = *(const ushort4*)&Pg[row * 96 + c4];
    }
    __syncthreads();

    const unsigned short* Vbase = Vb + (size_t)b * 4096 * 768 + h * 96;
    int mf = lane & 15, k8 = (lane >> 4) * 8;
    f32x4 acc[2][6] = {};
    #pragma unroll
    for (int k = 0; k < 3; k++) {
        bf16x8 a[2], bb[6];
        #pragma unroll
        for (int i = 0; i < 2; i++) {
            int row = ntile * 128 + w * 32 + i * 16 + mf;
            a[i] = *(const bf16x8*)&Vbase[(size_t)row * 768 + k * 32 + k8];
        }
        #pragma unroll
        for (int j = 0; j < 6; j++)
            bb[j] = *(const bf16x8*)&Ps[j * 16 + mf][k * 32 + k8];
        #pragma unroll
        for (int i = 0; i < 2; i++)
            #pragma unroll
            for (int j = 0; j < 6; j++)
                acc[i][j] = __builtin_amdgcn_mfma_f32_16x16x32_bf16(a[i], bb[j], acc[i][j], 0, 0, 0);
    }
    #pragma unroll
    for (int i = 0; i < 2; i++)
        #pragma unroll
        for (int j = 0; j < 6; j++)
            #pragma unroll
            for (int r = 0; r < 4; r++) {
                int n_tok = ntile * 128 + w * 32 + i * 16 + (lane >> 4) * 4 + r;
                int c = h * 96 + j * 16 + mf;
                X[((size_t)b * 4096 + n_tok) * 768 + c] = f2bf(acc[i][j][r]);
            }
}

// ---------------------------------------------------------------------------
extern "C" void kernel_launch(void* const* d_in, const int* in_sizes, int n_in,
                              void* d_out, int out_size, void* d_ws, size_t ws_size,
                              hipStream_t stream)
{
    (void)in_sizes; (void)n_in; (void)out_size; (void)ws_size;
    const float* ctx   = (const float*)d_in[0];
    const float* dep   = (const float*)d_in[1];
    const float* Wq    = (const float*)d_in[2];
    const float* Wkv   = (const float*)d_in[3];
    const float* Wproj = (const float*)d_in[4];
    const float* bproj = (const float*)d_in[5];
    float* out = (float*)d_out;

    char* p = (char*)d_ws;
    auto carve = [&](size_t bytes) {
        char* r = p;
        p += (bytes + 255) & ~(size_t)255;
        return r;
    };
    unsigned short* WqT    = (unsigned short*)carve((size_t)768 * 768 * 2);
    unsigned short* WkvT   = (unsigned short*)carve((size_t)1536 * 768 * 2);
    unsigned short* WprojT = (unsigned short*)carve((size_t)768 * 768 * 2);
    unsigned short* Qt     = (unsigned short*)carve((size_t)32 * 96 * 4096 * 2);
    unsigned short* Kt     = (unsigned short*)carve((size_t)32 * 96 * 4096 * 2);
    unsigned short* Vb     = (unsigned short*)carve((size_t)16384 * 768 * 2);
    unsigned short* Xb     = (unsigned short*)carve((size_t)16384 * 768 * 2);
    float*          ssq    = (float*)carve((size_t)2 * 3072 * 4);
    float*          Spart  = (float*)carve((size_t)32 * 16 * 9216 * 4);
    unsigned short* Pb     = (unsigned short*)carve((size_t)32 * 9216 * 2);
    unsigned short* depB   = (unsigned short*)carve((size_t)16384 * 768 * 2);
    // ctx-bf16 aliases Xb: Q-gemm consumes it before pv_gemm writes Xb.
    unsigned short* ctxB   = Xb;

    hipMemsetAsync(ssq, 0, 2 * 3072 * 4, stream);

    f32_to_bf16_k<<<6144, 256, 0, stream>>>(ctx, ctxB);
    f32_to_bf16_k<<<6144, 256, 0, stream>>>(dep, depB);

    dim3 tb(32, 8);
    transpose_to_bf16<<<dim3(24, 24), tb, 0, stream>>>(Wq, WqT, 768, 768);
    transpose_to_bf16<<<dim3(48, 24), tb, 0, stream>>>(Wkv, WkvT, 768, 1536);
    transpose_to_bf16<<<dim3(24, 24), tb, 0, stream>>>(Wproj, WprojT, 768, 768);

    gemm_bt<0><<<dim3(6, 128), 256, 0, stream>>>(ctxB, WqT, nullptr, Qt, nullptr, 16384, 768, 768);
    gemm_bt<1><<<dim3(12, 128), 256, 0, stream>>>(depB, WkvT, nullptr, Kt, Vb, 16384, 1536, 768);

    s_gemm<<<dim3(16, 32), 256, 0, stream>>>(Qt, Kt, Spart, ssq);
    softmax_k<<<32, 128, 0, stream>>>(Spart, ssq, Pb);
    pv_gemm<<<dim3(32, 32), 256, 0, stream>>>(Vb, Pb, Xb);
    gemm_bt<2><<<dim3(6, 128), 256, 0, stream>>>(Xb, WprojT, bproj, out, nullptr, 16384, 768, 768);
}

// Round 5
// 350.315 us; speedup vs baseline: 1.3356x; 1.0499x over previous
//
#include <hip/hip_runtime.h>

// ---------------------------------------------------------------------------
// Channel attention (XCA): B=4, N=4096, C=768, H=8, HD=96, fp32 in/out.
// R5: gemm = 2-barrier K-loop (R2 structure, empirically best) + fragment-
// order conflict-free LDS (R3/R4) + 16KB single buffer. softmax rewritten
// wave-per-row (768 blocks, was 32x128 latency-bound @116us). s-splits 8.
// ---------------------------------------------------------------------------

using bf16x8 = __attribute__((ext_vector_type(8))) short;
using f32x4  = __attribute__((ext_vector_type(4))) float;

#define SCALE_ 0.10206207261596575f   // 96^-0.5

__device__ __forceinline__ unsigned short f2bf(float f) {
    unsigned int u = __builtin_bit_cast(unsigned int, f);
    u += 0x7FFFu + ((u >> 16) & 1u);          // RNE, finite inputs only
    return (unsigned short)(u >> 16);
}
__device__ __forceinline__ float bf2f(unsigned short h) {
    unsigned int u = ((unsigned int)h) << 16;
    return __builtin_bit_cast(float, u);
}

__device__ __forceinline__ void glds16(const unsigned short* g, unsigned short* l) {
    __builtin_amdgcn_global_load_lds(
        (const __attribute__((address_space(1))) void*)g,
        (__attribute__((address_space(3))) void*)l, 16, 0, 0);
}

// sum of squares of 8 bf16 packed in a frag
__device__ __forceinline__ float ssq8(bf16x8 v) {
    uint4 u = __builtin_bit_cast(uint4, v);
    unsigned a[4] = {u.x, u.y, u.z, u.w};
    float s = 0.f;
    #pragma unroll
    for (int i = 0; i < 4; i++) {
        float lo = __builtin_bit_cast(float, a[i] << 16);
        float hi = __builtin_bit_cast(float, a[i] & 0xFFFF0000u);
        s += lo * lo + hi * hi;
    }
    return s;
}

// ---------------------------------------------------------------------------
// fp32 -> bf16 bulk convert (memory-bound). 8 elems/thread.
// ---------------------------------------------------------------------------
__global__ void f32_to_bf16_k(const float* __restrict__ in,
                              unsigned short* __restrict__ out)
{
    size_t idx = ((size_t)blockIdx.x * 256 + threadIdx.x) * 8;
    float4 v0 = *(const float4*)&in[idx];
    float4 v1 = *(const float4*)&in[idx + 4];
    unsigned short h[8];
    h[0] = f2bf(v0.x); h[1] = f2bf(v0.y); h[2] = f2bf(v0.z); h[3] = f2bf(v0.w);
    h[4] = f2bf(v1.x); h[5] = f2bf(v1.y); h[6] = f2bf(v1.z); h[7] = f2bf(v1.w);
    *(bf16x8*)&out[idx] = *(bf16x8*)h;
}

// ---------------------------------------------------------------------------
// Weight transpose + fp32->bf16: W[K][N] -> Wt[N][K]. block(32,8).
// ---------------------------------------------------------------------------
__global__ void transpose_to_bf16(const float* __restrict__ W,
                                  unsigned short* __restrict__ Wt,
                                  int K, int N)
{
    __shared__ float tile[32][33];
    int n0 = blockIdx.x * 32, k0 = blockIdx.y * 32;
    int tx = threadIdx.x, ty = threadIdx.y;
    #pragma unroll
    for (int i = 0; i < 32; i += 8)
        tile[ty + i][tx] = W[(size_t)(k0 + ty + i) * N + n0 + tx];
    __syncthreads();
    #pragma unroll
    for (int i = 0; i < 32; i += 8)
        Wt[(size_t)(n0 + ty + i) * K + k0 + tx] = f2bf(tile[tx][ty + i]);
}

// ---------------------------------------------------------------------------
// GEMM: C = A[M][K] * Bt[N][K]^T, bf16. 128x128 block, BK=32, 4 waves 2x2
// of 64x64 (4x4 16x16x32 MFMA). Fragment-order LDS: glds16 lane map
// (row=lane&15, kc=lane>>4) -> frag read is base + lane*16B, sequential,
// zero bank conflicts. 2-barrier K-loop (stage -> barrier -> compute ->
// barrier): empirically best (R2 62us vs R4-dbuf 85us). 16KB LDS.
// MODE 0: write transposed bf16 Qt[bh][d][n]     (out0)
// MODE 1: cols<768 -> Kt[bh][d][n] (out0); cols>=768 -> Vb[m][768] (out1)
// MODE 2: fp32 + bias row-major (out0)
// ---------------------------------------------------------------------------
template<int MODE>
__global__ __launch_bounds__(256) void gemm_bt(
    const unsigned short* __restrict__ A, const unsigned short* __restrict__ Bt,
    const float* __restrict__ bias, void* __restrict__ out0, void* __restrict__ out1,
    int M, int N, int K)
{
    __shared__ unsigned short As[128 * 32];   // 8 blocks of 1KB, fragment order
    __shared__ unsigned short Bs[128 * 32];

    const int Nt = gridDim.x, Mt = gridDim.y;
    const int lin = blockIdx.y * Nt + blockIdx.x;
    const int xcd = lin & 7, li = lin >> 3;
    const int band = Mt >> 3;
    const int mt = xcd * band + (li % band);
    const int nt = li / band;
    const int bm = mt * 128, bn = nt * 128;

    const int t = threadIdx.x, lane = t & 63, w = t >> 6;
    const int wm = (w >> 1) * 64, wn = (w & 1) * 64;
    const int mf = lane & 15, quad = lane >> 4;

    // staging lane map (fragment order): row = lane&15, k-off = (lane>>4)*8
    const int srow = lane & 15, skc = (lane >> 4) * 8;
    const unsigned short* gA = A  + (size_t)(bm + w * 32 + srow) * K + skc;
    const unsigned short* gB = Bt + (size_t)(bn + w * 32 + srow) * K + skc;

    f32x4 acc[4][4] = {};

    for (int k0 = 0; k0 < K; k0 += 32) {
        #pragma unroll
        for (int c = 0; c < 2; c++) {
            glds16(gA + (size_t)(c * 16) * K + k0, &As[(w * 2 + c) * 512]);
            glds16(gB + (size_t)(c * 16) * K + k0, &Bs[(w * 2 + c) * 512]);
        }
        __syncthreads();
        bf16x8 a[4], b[4];
        #pragma unroll
        for (int i = 0; i < 4; i++)
            a[i] = *(const bf16x8*)&As[(((w >> 1) * 4) + i) * 512 + lane * 8];
        #pragma unroll
        for (int j = 0; j < 4; j++)
            b[j] = *(const bf16x8*)&Bs[(((w & 1) * 4) + j) * 512 + lane * 8];
        #pragma unroll
        for (int i = 0; i < 4; i++)
            #pragma unroll
            for (int j = 0; j < 4; j++)
                acc[i][j] = __builtin_amdgcn_mfma_f32_16x16x32_bf16(a[i], b[j], acc[i][j], 0, 0, 0);
        __syncthreads();
    }

    // C/D layout: col = lane&15, row = quad*4 + r
    if constexpr (MODE == 2) {
        float* C = (float*)out0;
        #pragma unroll
        for (int i = 0; i < 4; i++) {
            int row0 = bm + wm + i * 16 + quad * 4;
            #pragma unroll
            for (int j = 0; j < 4; j++) {
                int col = bn + wn + j * 16 + mf;
                float bv = bias[col];
                #pragma unroll
                for (int r = 0; r < 4; r++)
                    C[(size_t)(row0 + r) * N + col] = acc[i][j][r] + bv;
            }
        }
    } else {
        unsigned short* Tr = (unsigned short*)out0;   // Qt or Kt [bh][96][4096]
        unsigned short* Vb = (unsigned short*)out1;   // [16384][768]
        const bool kpart = (MODE == 0) || (bn < 768);
        #pragma unroll
        for (int i = 0; i < 4; i++) {
            int row0 = bm + wm + i * 16 + quad * 4;   // global token index
            int bb = row0 >> 12, n = row0 & 4095;
            #pragma unroll
            for (int j = 0; j < 4; j++) {
                int c = bn + wn + j * 16 + mf;
                if (kpart) {
                    int h = (c * 683) >> 16;          // floor(c/96) for c<768
                    int d = c - h * 96;
                    size_t o = ((size_t)((bb * 8 + h) * 96 + d)) * 4096 + n;
                    ushort4 v4;
                    v4.x = f2bf(acc[i][j][0]); v4.y = f2bf(acc[i][j][1]);
                    v4.z = f2bf(acc[i][j][2]); v4.w = f2bf(acc[i][j][3]);
                    *(ushort4*)&Tr[o] = v4;
                } else {
                    int cv = c - 768;
                    #pragma unroll
                    for (int r = 0; r < 4; r++)
                        Vb[(size_t)(row0 + r) * 768 + cv] = f2bf(acc[i][j][r]);
                }
            }
        }
    }
}

// ---------------------------------------------------------------------------
// S-gram: Spart[bh][s][96][96] = sum over 512-n window of Qt[d][n]*Kt[e][n].
// n-contiguous operands -> glds16 fragment-order, no transpose. 4 waves 2x2
// of 48x48 (3x3 MFMA), BK=64 (2 ksteps/iter), 8 iters of 64 n, internal
// dbuf (1 block/CU -> no inter-block overlap to lean on). ssq fused from
// register frags. grid(8 splits, 32 bh).
// ---------------------------------------------------------------------------
__global__ __launch_bounds__(256) void s_gemm(
    const unsigned short* __restrict__ Qt, const unsigned short* __restrict__ Kt,
    float* __restrict__ Spart, float* __restrict__ ssq)
{
    __shared__ unsigned short Qs[2][12 * 512];
    __shared__ unsigned short Ks[2][12 * 512];
    const int s = blockIdx.x, bh = blockIdx.y;
    const int t = threadIdx.x, lane = t & 63, w = t >> 6;
    const int m0 = (w >> 1) * 48, n0w = (w & 1) * 48;
    const int mf = lane & 15, quad = lane >> 4;
    const int srow = lane & 15, skc = (lane >> 4) * 8;
    const int nwin = s * 512;

    const unsigned short* Qg = Qt + (size_t)bh * 96 * 4096;
    const unsigned short* Kg = Kt + (size_t)bh * 96 * 4096;

    f32x4 acc[3][3] = {};
    float sq[3] = {0.f, 0.f, 0.f}, sk[3] = {0.f, 0.f, 0.f};

    // prologue: wave w stages blocks w*3..w*3+2 per operand (bi = kc*6+g)
    #pragma unroll
    for (int c = 0; c < 3; c++) {
        int bi = w * 3 + c, kc = bi / 6, g = bi % 6;
        size_t go = (size_t)(g * 16 + srow) * 4096 + nwin + kc * 32 + skc;
        glds16(Qg + go, &Qs[0][bi * 512]);
        glds16(Kg + go, &Ks[0][bi * 512]);
    }

    for (int it = 0; it < 8; it++) {
        const int cur = it & 1;
        __syncthreads();
        if (it + 1 < 8) {
            const int nxt = cur ^ 1;
            const int nn = nwin + (it + 1) * 64;
            #pragma unroll
            for (int c = 0; c < 3; c++) {
                int bi = w * 3 + c, kc = bi / 6, g = bi % 6;
                size_t go = (size_t)(g * 16 + srow) * 4096 + nn + kc * 32 + skc;
                glds16(Qg + go, &Qs[nxt][bi * 512]);
                glds16(Kg + go, &Ks[nxt][bi * 512]);
            }
        }
        #pragma unroll
        for (int kk = 0; kk < 2; kk++) {
            bf16x8 a[3], b[3];
            #pragma unroll
            for (int i = 0; i < 3; i++)
                a[i] = *(const bf16x8*)&Qs[cur][(kk * 6 + (w >> 1) * 3 + i) * 512 + lane * 8];
            #pragma unroll
            for (int j = 0; j < 3; j++)
                b[j] = *(const bf16x8*)&Ks[cur][(kk * 6 + (w & 1) * 3 + j) * 512 + lane * 8];
            if ((w & 1) == 0) {                 // waves 0,2: Q rows m0..m0+47 (unique)
                #pragma unroll
                for (int i = 0; i < 3; i++) sq[i] += ssq8(a[i]);
            }
            if ((w >> 1) == 0) {                // waves 0,1: K rows n0w..n0w+47 (unique)
                #pragma unroll
                for (int j = 0; j < 3; j++) sk[j] += ssq8(b[j]);
            }
            #pragma unroll
            for (int i = 0; i < 3; i++)
                #pragma unroll
                for (int j = 0; j < 3; j++)
                    acc[i][j] = __builtin_amdgcn_mfma_f32_16x16x32_bf16(a[i], b[j], acc[i][j], 0, 0, 0);
        }
    }

    // ssq: quads hold disjoint n-chunks -> reduce across quads, lane<16 commits
    if ((w & 1) == 0) {
        #pragma unroll
        for (int i = 0; i < 3; i++) {
            float v = sq[i];
            v += __shfl_xor(v, 16, 64);
            v += __shfl_xor(v, 32, 64);
            if (lane < 16) atomicAdd(&ssq[bh * 96 + m0 + i * 16 + lane], v);
        }
    }
    if ((w >> 1) == 0) {
        #pragma unroll
        for (int j = 0; j < 3; j++) {
            float v = sk[j];
            v += __shfl_xor(v, 16, 64);
            v += __shfl_xor(v, 32, 64);
            if (lane < 16) atomicAdd(&ssq[3072 + bh * 96 + n0w + j * 16 + lane], v);
        }
    }

    float* outp = Spart + (size_t)(bh * 8 + s) * 9216;
    #pragma unroll
    for (int i = 0; i < 3; i++)
        #pragma unroll
        for (int j = 0; j < 3; j++) {
            int e  = n0w + j * 16 + mf;
            int d0 = m0 + i * 16 + quad * 4;
            #pragma unroll
            for (int r = 0; r < 4; r++)
                outp[(d0 + r) * 96 + e] = acc[i][j][r];
        }
}

// ---------------------------------------------------------------------------
// Softmax, wave-per-row: grid(24, 32bh) x 256 thr; wave w owns row
// d = bx*4+w of S[bh]. Lanes: e=lane and e=64+lane (lane<32). Coalesced
// 256B partial loads, shuffle-reduce max/sum. Replaces 116us latency-bound
// version (was 32 blocks x 128 thr with serial 96-loops).
// ---------------------------------------------------------------------------
__global__ __launch_bounds__(256) void softmax_k(
    const float* __restrict__ Spart, const float* __restrict__ ssq,
    unsigned short* __restrict__ P)
{
    const int bh = blockIdx.y;
    const int d  = blockIdx.x * 4 + (threadIdx.x >> 6);
    const int lane = threadIdx.x & 63;

    const float sr = SCALE_ / fmaxf(sqrtf(ssq[bh * 96 + d]), 1e-12f);

    const float* Sp = Spart + (size_t)bh * 8 * 9216 + d * 96;
    float sa = 0.f, sb = 0.f;
    #pragma unroll
    for (int ch = 0; ch < 8; ch++) {
        sa += Sp[ch * 9216 + lane];
        if (lane < 32) sb += Sp[ch * 9216 + 64 + lane];
    }
    float ka = 1.0f / fmaxf(sqrtf(ssq[3072 + bh * 96 + lane]), 1e-12f);
    float va = sa * sr * ka;
    float vb = -1e30f;
    if (lane < 32) {
        float kb = 1.0f / fmaxf(sqrtf(ssq[3072 + bh * 96 + 64 + lane]), 1e-12f);
        vb = sb * sr * kb;
    }

    float m = fmaxf(va, vb);
    #pragma unroll
    for (int off = 32; off >= 1; off >>= 1)
        m = fmaxf(m, __shfl_xor(m, off, 64));

    float ea = __expf(va - m);
    float eb = (lane < 32) ? __expf(vb - m) : 0.f;
    float ssum = ea + eb;
    #pragma unroll
    for (int off = 32; off >= 1; off >>= 1)
        ssum += __shfl_xor(ssum, off, 64);

    float inv = 1.0f / ssum;
    unsigned short* Pr = P + (size_t)bh * 9216 + d * 96;
    Pr[lane] = f2bf(ea * inv);
    if (lane < 32) Pr[64 + lane] = f2bf(eb * inv);
}

// ---------------------------------------------------------------------------
// x[n][d] = sum_e V[n][e] * P[d][e] per (b,h). V from compact Vb[m][768].
// ---------------------------------------------------------------------------
__global__ __launch_bounds__(256) void pv_gemm(
    const unsigned short* __restrict__ Vb, const unsigned short* __restrict__ P,
    unsigned short* __restrict__ X)
{
    __shared__ unsigned short Ps[96][104];
    int ntile = blockIdx.x, bh = blockIdx.y;
    int b = bh >> 3, h = bh & 7;
    int t = threadIdx.x, lane = t & 63, w = t >> 6;

    const unsigned short* Pg = P + (size_t)bh * 9216;
    #pragma unroll
    for (int i = 0; i < 9; i++) {
        int idx4 = t + 256 * i;                 // 2304 ushort4 chunks
        int row = idx4 / 24, c4 = (idx4 - row * 24) * 4;
        *(ushort4*)&Ps[row][c4] = *(const ushort4*)&Pg[row * 96 + c4];
    }
    __syncthreads();

    const unsigned short* Vbase = Vb + (size_t)b * 4096 * 768 + h * 96;
    int mf = lane & 15, k8 = (lane >> 4) * 8;
    f32x4 acc[2][6] = {};
    #pragma unroll
    for (int k = 0; k < 3; k++) {
        bf16x8 a[2], bb[6];
        #pragma unroll
        for (int i = 0; i < 2; i++) {
            int row = ntile * 128 + w * 32 + i * 16 + mf;
            a[i] = *(const bf16x8*)&Vbase[(size_t)row * 768 + k * 32 + k8];
        }
        #pragma unroll
        for (int j = 0; j < 6; j++)
            bb[j] = *(const bf16x8*)&Ps[j * 16 + mf][k * 32 + k8];
        #pragma unroll
        for (int i = 0; i < 2; i++)
            #pragma unroll
            for (int j = 0; j < 6; j++)
                acc[i][j] = __builtin_amdgcn_mfma_f32_16x16x32_bf16(a[i], bb[j], acc[i][j], 0, 0, 0);
    }
    #pragma unroll
    for (int i = 0; i < 2; i++)
        #pragma unroll
        for (int j = 0; j < 6; j++)
            #pragma unroll
            for (int r = 0; r < 4; r++) {
                int n_tok = ntile * 128 + w * 32 + i * 16 + (lane >> 4) * 4 + r;
                int c = h * 96 + j * 16 + mf;
                X[((size_t)b * 4096 + n_tok) * 768 + c] = f2bf(acc[i][j][r]);
            }
}

// ---------------------------------------------------------------------------
extern "C" void kernel_launch(void* const* d_in, const int* in_sizes, int n_in,
                              void* d_out, int out_size, void* d_ws, size_t ws_size,
                              hipStream_t stream)
{
    (void)in_sizes; (void)n_in; (void)out_size; (void)ws_size;
    const float* ctx   = (const float*)d_in[0];
    const float* dep   = (const float*)d_in[1];
    const float* Wq    = (const float*)d_in[2];
    const float* Wkv   = (const float*)d_in[3];
    const float* Wproj = (const float*)d_in[4];
    const float* bproj = (const float*)d_in[5];
    float* out = (float*)d_out;

    char* p = (char*)d_ws;
    auto carve = [&](size_t bytes) {
        char* r = p;
        p += (bytes + 255) & ~(size_t)255;
        return r;
    };
    unsigned short* WqT    = (unsigned short*)carve((size_t)768 * 768 * 2);
    unsigned short* WkvT   = (unsigned short*)carve((size_t)1536 * 768 * 2);
    unsigned short* WprojT = (unsigned short*)carve((size_t)768 * 768 * 2);
    unsigned short* Qt     = (unsigned short*)carve((size_t)32 * 96 * 4096 * 2);
    unsigned short* Kt     = (unsigned short*)carve((size_t)32 * 96 * 4096 * 2);
    unsigned short* Vb     = (unsigned short*)carve((size_t)16384 * 768 * 2);
    unsigned short* Xb     = (unsigned short*)carve((size_t)16384 * 768 * 2);
    float*          ssq    = (float*)carve((size_t)2 * 3072 * 4);
    float*          Spart  = (float*)carve((size_t)32 * 8 * 9216 * 4);
    unsigned short* Pb     = (unsigned short*)carve((size_t)32 * 9216 * 2);
    unsigned short* depB   = (unsigned short*)carve((size_t)16384 * 768 * 2);
    // ctx-bf16 aliases Xb: Q-gemm consumes it before pv_gemm writes Xb.
    unsigned short* ctxB   = Xb;

    hipMemsetAsync(ssq, 0, 2 * 3072 * 4, stream);

    f32_to_bf16_k<<<6144, 256, 0, stream>>>(ctx, ctxB);
    f32_to_bf16_k<<<6144, 256, 0, stream>>>(dep, depB);

    dim3 tb(32, 8);
    transpose_to_bf16<<<dim3(24, 24), tb, 0, stream>>>(Wq, WqT, 768, 768);
    transpose_to_bf16<<<dim3(48, 24), tb, 0, stream>>>(Wkv, WkvT, 768, 1536);
    transpose_to_bf16<<<dim3(24, 24), tb, 0, stream>>>(Wproj, WprojT, 768, 768);

    gemm_bt<0><<<dim3(6, 128), 256, 0, stream>>>(ctxB, WqT, nullptr, Qt, nullptr, 16384, 768, 768);
    gemm_bt<1><<<dim3(12, 128), 256, 0, stream>>>(depB, WkvT, nullptr, Kt, Vb, 16384, 1536, 768);

    s_gemm<<<dim3(8, 32), 256, 0, stream>>>(Qt, Kt, Spart, ssq);
    softmax_k<<<dim3(24, 32), 256, 0, stream>>>(Spart, ssq, Pb);
    pv_gemm<<<dim3(32, 32), 256, 0, stream>>>(Vb, Pb, Xb);
    gemm_bt<2><<<dim3(6, 128), 256, 0, stream>>>(Xb, WprojT, bproj, out, nullptr, 16384, 768, 768);
}